// Round 3
// baseline (36.533 us; speedup 1.0000x reference)
//
#include <hip/hip_runtime.h>

namespace {
constexpr int W = 512, H = 512, D = 8, B = 4;
constexpr int HW  = H * W;
constexpr int DHW = D * HW;
constexpr long YBASE = (long)B * 3 * DHW;  // coords_max elements before y_max
typedef float f32x4 __attribute__((ext_vector_type(4)));
}

struct Slab4 {                 // 4 y-rows (y0-1..y0+2) of one z-slab, x0-1..x0+4
  f32x4 v[4];
  float l[4], r[4];            // clamped x halos
};

// Z-MARCH: wave owns a fixed 4-row y-window (outputs rows y0,y0+1; x=4/lane,
// half-W) and marches z=0..7 with a 3-slot slab ring, prefetching slab z+2
// during compute of z. Each wave reads every slab exactly once -> the 3x
// z-re-read amplification of the y-march kernel is eliminated at the source
// (fabric read traffic 151 MB -> 67 MB; total 285 -> 201 MB). 2048 waves
// (4b x 256 ypairs x 2 halves) = 8 waves/CU, all resident, zero tail.
// LB(256,2): 256-VGPR budget -> no spill risk for the ~150-reg peak
// (72-reg window + 24-reg prefetch + temps); residency is grid-limited,
// not VGPR-limited, so the cap costs nothing.
__global__ __launch_bounds__(256, 2) void cqi3d(const float* __restrict__ x,
                                                float* __restrict__ out) {
  int t = blockIdx.x * 256 + threadIdx.x;
  int lane = t & 63;
  int wid = t >> 6;                    // 2048 waves
  int half  = wid & 1;
  int ypair = (wid >> 1) & 255;        // adjacent ypairs share a block -> L2 halo reuse
  int b     = wid >> 9;
  int y0 = ypair << 1;
  int x0 = half * 256 + lane * 4;

  const float* xb = x + (size_t)b * DHW;
  int xm = (x0 == 0) ? 0 : -1;          // clamped x-1 offset
  int xp = (x0 == W - 4) ? 3 : 4;       // clamped x+4 offset
  int yw[4];                            // clamped input-row offsets y0-1..y0+2
  yw[0] = (y0 == 0 ? 0 : y0 - 1) * W;
  yw[1] = y0 * W;
  yw[2] = (y0 + 1) * W;
  yw[3] = (y0 + 2 > H - 1 ? H - 1 : y0 + 2) * W;

  float w[3][4][6];                    // [zslot][yrow][xc], xc = x0-1..x0+4

  auto fetchSlab = [&](int zs) -> Slab4 {
    const float* sp = xb + (size_t)zs * HW + x0;
    Slab4 s;
#pragma unroll
    for (int i = 0; i < 4; ++i) {
      const float* p = sp + yw[i];
      s.v[i] = *reinterpret_cast<const f32x4*>(p);
      s.l[i] = p[xm];
      s.r[i] = p[xp];
    }
    return s;
  };
  auto commit = [&](int slot, const Slab4& s) {
#pragma unroll
    for (int i = 0; i < 4; ++i) {
      w[slot][i][0] = s.l[i];
      w[slot][i][1] = s.v[i].x; w[slot][i][2] = s.v[i].y;
      w[slot][i][3] = s.v[i].z; w[slot][i][4] = s.v[i].w;
      w[slot][i][5] = s.r[i];
    }
  };

  float* ob = out + (size_t)b * 3 * DHW;
  float* yb = out + YBASE + (size_t)b * DHW;
  float xf = (float)x0;

  // compute both output rows for plane z; sm/sc/sp_ are compile-time slot ids
  auto computeZ = [&](int z, int sm, int sc, int sp_) {
    float zf = (float)z;
    // per-column max over the 3 z-slots for each window row, then combine
    // into the two rows' 3(y)x3(z) column maxes (rows 1,2 shared)
    float cmv[2][6];
#pragma unroll
    for (int q = 0; q < 6; ++q) {
      float a0 = fmaxf(fmaxf(w[sm][0][q], w[sc][0][q]), w[sp_][0][q]);
      float a1 = fmaxf(fmaxf(w[sm][1][q], w[sc][1][q]), w[sp_][1][q]);
      float a2 = fmaxf(fmaxf(w[sm][2][q], w[sc][2][q]), w[sp_][2][q]);
      float a3 = fmaxf(fmaxf(w[sm][3][q], w[sc][3][q]), w[sp_][3][q]);
      float m12 = fmaxf(a1, a2);
      cmv[0][q] = fmaxf(a0, m12);
      cmv[1][q] = fmaxf(m12, a3);
    }
#pragma unroll
    for (int r = 0; r < 2; ++r) {
      float ods[4], odx[4], ody[4], oym[4];
#pragma unroll
      for (int k = 0; k < 4; ++k) {
        float c  = w[sc][r + 1][k + 1];
        float bx = 0.5f * (w[sc][r + 1][k + 2] - w[sc][r + 1][k]);
        float by = 0.5f * (w[sc][r + 2][k + 1] - w[sc][r][k + 1]);
        float bs = 0.5f * (w[sp_][r + 1][k + 1] - w[sm][r + 1][k + 1]);
        float a  = w[sc][r + 1][k + 2] - 2.0f * c + w[sc][r + 1][k];      // dxx
        float b_ = w[sc][r + 2][k + 1] - 2.0f * c + w[sc][r][k + 1];      // dyy
        float c_ = w[sp_][r + 1][k + 1] - 2.0f * c + w[sm][r + 1][k + 1]; // dss
        float dxy = w[sc][r][k] - w[sc][r][k + 2] - w[sc][r + 2][k] + w[sc][r + 2][k + 2];
        float dys = w[sm][r][k + 1] - w[sm][r + 2][k + 1] - w[sp_][r][k + 1] + w[sp_][r + 2][k + 1];
        float dxs = w[sm][r + 1][k] - w[sm][r + 1][k + 2] - w[sp_][r + 1][k] + w[sp_][r + 1][k + 2];
        float d_ = 0.25f * dxy, f_ = 0.25f * dys, e_ = 0.25f * dxs;

        // adjugate solve of symmetric [[a,d,e],[d,b,f],[e,f,c]]
        float cof0 = b_ * c_ - f_ * f_;
        float cof1 = e_ * f_ - d_ * c_;
        float cof2 = d_ * f_ - e_ * b_;
        float det = a * cof0 - d_ * (d_ * c_ - f_ * e_) + e_ * cof2;
        bool ok = fabsf(det) > 1e-7f;
        float sd = ok ? det : 1.0f;
        float inv = __builtin_amdgcn_rcpf(sd);  // approx rcp; well within threshold
        float sx = (cof0 * bx + cof1 * by + cof2 * bs) * inv;
        float sy = (cof1 * bx + (a * c_ - e_ * e_) * by + (e_ * d_ - a * f_) * bs) * inv;
        float ss = (cof2 * bx + (e_ * d_ - a * f_) * by + (a * b_ - d_ * d_) * bs) * inv;

        float mx = fmaxf(fmaxf(cmv[r][k], cmv[r][k + 1]), cmv[r][k + 2]);
        bool newm = (c == mx) && ok;
        float dxv = newm ? -sx : 0.0f;
        float dyv = newm ? -sy : 0.0f;
        float dsv = newm ? -ss : 0.0f;
        bool over = fmaxf(fmaxf(fabsf(dxv), fabsf(dyv)), fabsf(dsv)) > 0.7f;
        if (over) { dxv = 0.0f; dyv = 0.0f; dsv = 0.0f; }
        float dy_val = 0.5f * (bx * dxv + by * dyv + bs * dsv);
        ods[k] = dsv;
        odx[k] = dxv;
        ody[k] = dyv;
        oym[k] = c + dy_val + (newm ? 10.0f : 0.0f);
      }
      int so = z * HW + (y0 + r) * W + x0;
      float yf = (float)(y0 + r);
      // nontemporal: outputs are never re-read; keep L2/L3 for the input
      f32x4 v0 = { ods[0] + zf, ods[1] + zf, ods[2] + zf, ods[3] + zf };
      f32x4 v1 = { odx[0] + xf, odx[1] + xf + 1.0f, odx[2] + xf + 2.0f, odx[3] + xf + 3.0f };
      f32x4 v2 = { ody[0] + yf, ody[1] + yf, ody[2] + yf, ody[3] + yf };
      f32x4 v3 = { oym[0], oym[1], oym[2], oym[3] };
      __builtin_nontemporal_store(v0, reinterpret_cast<f32x4*>(ob + so));
      __builtin_nontemporal_store(v1, reinterpret_cast<f32x4*>(ob + so + DHW));
      __builtin_nontemporal_store(v2, reinterpret_cast<f32x4*>(ob + so + 2 * DHW));
      __builtin_nontemporal_store(v3, reinterpret_cast<f32x4*>(yb + so));
    }
  };

  // prologue: issue slabs 0,1,2 back-to-back (overlapped latency)
  Slab4 s0 = fetchSlab(0);
  Slab4 s1 = fetchSlab(1);
  Slab4 s2 = fetchSlab(2);
  commit(0, s0);
  commit(1, s1);
  computeZ(0, 0, 0, 1);                // z=0: slabs (0,0,1) — replicate pad
  commit(2, s2);

  // z=1..6 in two rolled groups of 3 (slot pattern period 3; keeps code
  // ~I-cache-sized while all w[] indices stay compile-time constants)
#pragma unroll 1
  for (int grp = 0; grp < 2; ++grp) {
    int zbase = 1 + grp * 3;
#pragma unroll
    for (int j = 0; j < 3; ++j) {
      int z = zbase + j;
      Slab4 pf;
      bool more = (z <= 5);            // slab z+2 exists
      if (more) pf = fetchSlab(z + 2); // prefetch BEFORE compute (hides latency)
      computeZ(z, j, (j + 1) % 3, (j + 2) % 3);
      if (more) commit(j, pf);         // retire slab z-1's slot
    }
  }
  computeZ(7, 0, 1, 1);                // z=7: slabs (6,7,7) — replicate pad
}

extern "C" void kernel_launch(void* const* d_in, const int* in_sizes, int n_in,
                              void* d_out, int out_size, void* d_ws, size_t ws_size,
                              hipStream_t stream) {
  const float* x = (const float*)d_in[0];
  float* out = (float*)d_out;
  // 2048 waves: (b, ypair, half) x z-march -> 131072 threads
  dim3 grid(512), block(256);
  hipLaunchKernelGGL(cqi3d, grid, block, 0, stream, x, out);
}

// Round 4
// 31.701 us; speedup vs baseline: 1.1524x; 1.1524x over previous
//
#include <hip/hip_runtime.h>

namespace {
constexpr int W = 512, H = 512, D = 8, B = 4;
constexpr int HW  = H * W;
constexpr int DHW = D * HW;
constexpr long YBASE = (long)B * 3 * DHW;  // coords_max elements before y_max
typedef float f32x4 __attribute__((ext_vector_type(4)));
}

struct Row3 {               // one y-row across the 3 z-slabs
  f32x4 a, b, c;            // aligned float4 at x0 for z-1, z, z+1
  float ea, eb, ec;         // wave-edge value (x=256 for half0, x=255 for half1)
};

// R0 structure (x=4/lane, y-march, early prefetch, LB(256,3)) with the 36
// strided halo loads per wave replaced by cross-lane shuffles:
//   lane l's left halo  = lane l-1's v.w   (ds_bpermute, LDS pipe: idle here)
//   lane l's right halo = lane l+1's v.x
// Only the wave-boundary element (x=256 / x=255, owned by the sibling wave)
// still needs a load -- one 1-cacheline wave-uniform load per slab-row.
// L1 line-touch work per wave drops ~2.8x (864 -> ~310 lines); HBM traffic
// is unchanged. Targets the last un-probed resource (VMEM/L1 issue path).
__global__ __launch_bounds__(256, 3) void cqi3d(const float* __restrict__ x,
                                                float* __restrict__ out) {
  int t = blockIdx.x * 256 + threadIdx.x;
  int lane = t & 63;
  int wid = t >> 6;              // 8192 waves
  int half = wid & 1;            // x half: 0..1
  int y0 = ((wid >> 1) & 127) << 2;
  int z  = (wid >> 8) & 7;
  int b  = wid >> 11;
  int x0 = half * 256 + lane * 4;

  int zm1 = z > 0 ? z - 1 : 0, zp1 = z < D - 1 ? z + 1 : D - 1;
  const float* sb0 = x + (size_t)b * DHW + (size_t)zm1 * HW + x0;  // z-1
  const float* sb1 = x + (size_t)b * DHW + (size_t)z   * HW + x0;  // z
  const float* sb2 = x + (size_t)b * DHW + (size_t)zp1 * HW + x0;  // z+1
  // uniform-address edge element, expressed relative to the per-lane pointer:
  // half0 -> x=256 (right edge), half1 -> x=255 (left edge)
  int eo = (half ? 255 : 256) - x0;
  int lm = lane - 1, lp = lane + 1;
  bool l0 = (lane == 0), l63 = (lane == 63);

  float w[3][3][6];  // [yslot][iz][xc], xc covers x0-1 .. x0+4

  auto fetch = [&](int yq) -> Row3 {
    int yc = yq < 0 ? 0 : (yq > H - 1 ? H - 1 : yq);
    const float* p0 = sb0 + (size_t)yc * W;
    const float* p1 = sb1 + (size_t)yc * W;
    const float* p2 = sb2 + (size_t)yc * W;
    Row3 r;
    r.a = *reinterpret_cast<const f32x4*>(p0); r.ea = p0[eo];
    r.b = *reinterpret_cast<const f32x4*>(p1); r.eb = p1[eo];
    r.c = *reinterpret_cast<const f32x4*>(p2); r.ec = p2[eo];
    return r;
  };
  auto commit = [&](int slot, const Row3& r) {
    // halos from neighbor lanes; wave-edge / global-edge handled by selects.
    // left  halo: lane0 gets (half? sibling-wave edge : clamp to own .x)
    // right halo: lane63 gets (half? clamp to own .w : sibling-wave edge)
    float lnA = __shfl(r.a.w, lm), rnA = __shfl(r.a.x, lp);
    float lnB = __shfl(r.b.w, lm), rnB = __shfl(r.b.x, lp);
    float lnC = __shfl(r.c.w, lm), rnC = __shfl(r.c.x, lp);
    w[slot][0][0] = l0  ? (half ? r.ea : r.a.x) : lnA;
    w[slot][0][1] = r.a.x; w[slot][0][2] = r.a.y;
    w[slot][0][3] = r.a.z; w[slot][0][4] = r.a.w;
    w[slot][0][5] = l63 ? (half ? r.a.w : r.ea) : rnA;
    w[slot][1][0] = l0  ? (half ? r.eb : r.b.x) : lnB;
    w[slot][1][1] = r.b.x; w[slot][1][2] = r.b.y;
    w[slot][1][3] = r.b.z; w[slot][1][4] = r.b.w;
    w[slot][1][5] = l63 ? (half ? r.b.w : r.eb) : rnB;
    w[slot][2][0] = l0  ? (half ? r.ec : r.c.x) : lnC;
    w[slot][2][1] = r.c.x; w[slot][2][2] = r.c.y;
    w[slot][2][3] = r.c.z; w[slot][2][4] = r.c.w;
    w[slot][2][5] = l63 ? (half ? r.c.w : r.ec) : rnC;
  };

  { Row3 r = fetch(y0 - 1); commit(0, r); }
  { Row3 r = fetch(y0);     commit(1, r); }
  { Row3 r = fetch(y0 + 1); commit(2, r); }

  float zf = (float)z;
#pragma unroll
  for (int g = 0; g < 4; ++g) {
    int jm = g % 3, jc = (g + 1) % 3, jp = (g + 2) % 3;
    int y = y0 + g;

    Row3 pf;                       // prefetch y+2 BEFORE compute (hides latency)
    if (g < 3) pf = fetch(y + 2);

    const float (&wm)[3][6] = w[jm];  // y-1
    const float (&wc)[3][6] = w[jc];  // y
    const float (&wp)[3][6] = w[jp];  // y+1

    // shared column maxes over the 9 (y,z) rows
    float cm[6];
#pragma unroll
    for (int q = 0; q < 6; ++q) {
      float m0 = fmaxf(fmaxf(wm[0][q], wm[1][q]), wm[2][q]);
      float m1 = fmaxf(fmaxf(wc[0][q], wc[1][q]), wc[2][q]);
      float m2 = fmaxf(fmaxf(wp[0][q], wp[1][q]), wp[2][q]);
      cm[q] = fmaxf(fmaxf(m0, m1), m2);
    }

    float ods[4], odx[4], ody[4], oym[4];
#pragma unroll
    for (int k = 0; k < 4; ++k) {
      float c  = wc[1][k + 1];
      float bx = 0.5f * (wc[1][k + 2] - wc[1][k]);
      float by = 0.5f * (wp[1][k + 1] - wm[1][k + 1]);
      float bs = 0.5f * (wc[2][k + 1] - wc[0][k + 1]);
      float a  = wc[1][k + 2] - 2.0f * c + wc[1][k];        // dxx
      float b_ = wp[1][k + 1] - 2.0f * c + wm[1][k + 1];    // dyy
      float c_ = wc[2][k + 1] - 2.0f * c + wc[0][k + 1];    // dss
      float dxy = wm[1][k] - wm[1][k + 2] - wp[1][k] + wp[1][k + 2];
      float dys = wm[0][k + 1] - wp[0][k + 1] - wm[2][k + 1] + wp[2][k + 1];
      float dxs = wc[0][k] - wc[0][k + 2] - wc[2][k] + wc[2][k + 2];
      float d_ = 0.25f * dxy, f_ = 0.25f * dys, e_ = 0.25f * dxs;

      // adjugate solve of symmetric [[a,d,e],[d,b,f],[e,f,c]]
      float cof0 = b_ * c_ - f_ * f_;
      float cof1 = e_ * f_ - d_ * c_;
      float cof2 = d_ * f_ - e_ * b_;
      float det = a * cof0 - d_ * (d_ * c_ - f_ * e_) + e_ * cof2;
      bool ok = fabsf(det) > 1e-7f;
      float sd = ok ? det : 1.0f;
      float inv = __builtin_amdgcn_rcpf(sd);  // approx rcp; well within threshold
      float sx = (cof0 * bx + cof1 * by + cof2 * bs) * inv;
      float sy = (cof1 * bx + (a * c_ - e_ * e_) * by + (e_ * d_ - a * f_) * bs) * inv;
      float ss = (cof2 * bx + (e_ * d_ - a * f_) * by + (a * b_ - d_ * d_) * bs) * inv;

      float mx = fmaxf(fmaxf(cm[k], cm[k + 1]), cm[k + 2]);
      bool newm = (c == mx) && ok;
      float dxv = newm ? -sx : 0.0f;
      float dyv = newm ? -sy : 0.0f;
      float dsv = newm ? -ss : 0.0f;
      bool over = fmaxf(fmaxf(fabsf(dxv), fabsf(dyv)), fabsf(dsv)) > 0.7f;
      if (over) { dxv = 0.0f; dyv = 0.0f; dsv = 0.0f; }
      float dy_val = 0.5f * (bx * dxv + by * dyv + bs * dsv);
      ods[k] = dsv;
      odx[k] = dxv;
      ody[k] = dyv;
      oym[k] = c + dy_val + (newm ? 10.0f : 0.0f);
    }

    size_t s  = (size_t)z * HW + (size_t)y * W + x0;
    size_t cb = (size_t)b * 3 * DHW + s;
    float yf = (float)y, xf = (float)x0;
    // nontemporal: outputs are never re-read; keep L2/L3 for the input
    f32x4 v0 = { ods[0] + zf, ods[1] + zf, ods[2] + zf, ods[3] + zf };
    f32x4 v1 = { odx[0] + xf, odx[1] + xf + 1.0f, odx[2] + xf + 2.0f, odx[3] + xf + 3.0f };
    f32x4 v2 = { ody[0] + yf, ody[1] + yf, ody[2] + yf, ody[3] + yf };
    f32x4 v3 = { oym[0], oym[1], oym[2], oym[3] };
    __builtin_nontemporal_store(v0, reinterpret_cast<f32x4*>(out + cb));
    __builtin_nontemporal_store(v1, reinterpret_cast<f32x4*>(out + cb + DHW));
    __builtin_nontemporal_store(v2, reinterpret_cast<f32x4*>(out + cb + 2 * DHW));
    __builtin_nontemporal_store(v3, reinterpret_cast<f32x4*>(out + YBASE + (size_t)b * DHW + s));

    if (g < 3) commit(jm, pf);  // retire y-1 slot, bring in y+2
  }
}

extern "C" void kernel_launch(void* const* d_in, const int* in_sizes, int n_in,
                              void* d_out, int out_size, void* d_ws, size_t ws_size,
                              hipStream_t stream) {
  const float* x = (const float*)d_in[0];
  float* out = (float*)d_out;
  // 8192 waves: (b,z,ygroup,half) -> 524288 threads
  dim3 grid(2048), block(256);
  hipLaunchKernelGGL(cqi3d, grid, block, 0, stream, x, out);
}